// Round 2
// baseline (494.932 us; speedup 1.0000x reference)
//
#include <hip/hip_runtime.h>
#include <hip/hip_bf16.h>

// InteractionBlock: B=16,N=192,H=128,F=128,G=50
//   fw  = softplus(rbf@W1+b1)@W2+b2          [B,N,N,F]   (never materialized)
//   nf  = features@Wf+bf                      [B,N,F]
//   agg = sum_j mask[b,i,j]*fw[b,i,j,:]*nf[b,j,:]
//   out = features + softplus(agg@Wo1+bo1)@Wo2+bo2
//
// v3 changes vs v2:
//  - main: ballot-based compaction (no serial LDS atomics).
//  - main: rbf active rows staged to LDS via coalesced 50-lane row loads
//    (bf16, [row][64] XOR-swizzled) -> GEMM1 A-operand from LDS, not HBM.
//  - main: per-wave fused tile pipeline (G1 -> softplus -> private 4KB LDS
//    transpose buffer -> G2 -> nf-weighted reduce into registers); no
//    barriers in main loop, no LDS atomics; shuffle+LDS final reduction.
//  - main: dropped forced (256,3) launch bound (spill suspect in v2).

typedef __bf16 bf16_t;
typedef __bf16 bf16x8 __attribute__((ext_vector_type(8)));
typedef float  f32x4  __attribute__((ext_vector_type(4)));

constexpr int kB = 16, kN = 192, kH = 128, kF = 128, kG = 50;
constexpr int kRows = kB * kN;        // 3072
constexpr int kOutPitch = 136;        // bf16 elems, mult of 8 -> aligned b128

__device__ __forceinline__ float ldf(const void* p, int i, bool bfm) {
  return bfm ? (float)((const bf16_t*)p)[i] : ((const float*)p)[i];
}

__device__ __forceinline__ float softplus_f(float x) {
  float t = __logf(1.f + __expf(fminf(x, 20.f)));
  return x > 20.f ? x : t;
}

// ---- dtype detector: flag=1 if inputs are packed bf16, 0 if fp32 ----
__global__ __launch_bounds__(256) void detect_kernel(const unsigned int* __restrict__ rbf_w,
                                                     int* __restrict__ flag) {
  __shared__ int c_hi, c_zero;
  const int t = threadIdx.x;
  if (t == 0) { c_hi = 0; c_zero = 0; }
  __syncthreads();
  unsigned int w = rbf_w[(size_t)t * 40003u];   // in-bounds for both dtypes
  unsigned int lo = w & 0xFFFFu;
  if (((lo >> 7) & 0xFFu) >= 128u) atomicAdd(&c_hi, 1);   // |bf16| >= 2: impossible for rbf in [0,1)
  if (lo == 0u) atomicAdd(&c_zero, 1);
  __syncthreads();
  if (t == 0) *flag = (c_hi == 0 && c_zero < 200) ? 1 : 0;
}

// ---- transpose all weight matrices into bf16 [n][k] ----
__global__ __launch_bounds__(256) void prep_kernel(
    const void* __restrict__ W1, const void* __restrict__ W2,
    const void* __restrict__ Wf, const void* __restrict__ Wo1,
    const void* __restrict__ Wo2, const int* __restrict__ flag,
    bf16_t* __restrict__ w1t, bf16_t* __restrict__ w2t,
    bf16_t* __restrict__ wft, bf16_t* __restrict__ wo1t,
    bf16_t* __restrict__ wo2t) {
  const bool bfm = *flag != 0;
  int idx = blockIdx.x * 256 + threadIdx.x;
  if (idx < 8192) {                       // w1t
    int n = idx >> 6, k = idx & 63;
    w1t[idx] = (k < kG) ? (bf16_t)ldf(W1, k * kF + n, bfm) : (bf16_t)0.f;
  } else if (idx < 8192 + 16384) {        // w2t
    int i2 = idx - 8192; int n = i2 >> 7, k = i2 & 127;
    w2t[i2] = (bf16_t)ldf(W2, k * kF + n, bfm);
  } else if (idx < 8192 + 2 * 16384) {    // wft
    int i2 = idx - 8192 - 16384; int n = i2 >> 7, k = i2 & 127;
    wft[i2] = (bf16_t)ldf(Wf, k * kF + n, bfm);
  } else if (idx < 8192 + 3 * 16384) {    // wo1t
    int i2 = idx - 8192 - 2 * 16384; int n = i2 >> 7, k = i2 & 127;
    wo1t[i2] = (bf16_t)ldf(Wo1, k * kH + n, bfm);
  } else if (idx < 8192 + 4 * 16384) {    // wo2t
    int i2 = idx - 8192 - 3 * 16384; int n = i2 >> 7, k = i2 & 127;
    wo2t[i2] = (bf16_t)ldf(Wo2, k * kH + n, bfm);
  }
}

// ---- nf = features @ Wf + bf  (MFMA; fp32 result) ----
__global__ __launch_bounds__(128) void nf_kernel(const void* __restrict__ features,
                                                 const bf16_t* __restrict__ wft,
                                                 const void* __restrict__ bfv,
                                                 const int* __restrict__ flag,
                                                 float* __restrict__ nf) {
  const bool bfm = *flag != 0;
  const int t = threadIdx.x, wave = t >> 6, lane = t & 63;
  const int n16 = lane & 15, q = lane >> 4;
  const int rbase = blockIdx.x * 32 + wave * 16;
  const int arow = rbase + n16;

  f32x4 acc[8];
#pragma unroll
  for (int nt = 0; nt < 8; ++nt)
#pragma unroll
    for (int r = 0; r < 4; ++r) acc[nt][r] = 0.f;

  if (bfm) {
    const bf16_t* fp = (const bf16_t*)features + (size_t)arow * kH;
#pragma unroll
    for (int ks = 0; ks < 4; ++ks) {
      bf16x8 afr = *(const bf16x8*)(fp + ks * 32 + q * 8);
#pragma unroll
      for (int nt = 0; nt < 8; ++nt) {
        bf16x8 bfr = *(const bf16x8*)(wft + (nt * 16 + n16) * kH + ks * 32 + q * 8);
        acc[nt] = __builtin_amdgcn_mfma_f32_16x16x32_bf16(afr, bfr, acc[nt], 0, 0, 0);
      }
    }
  } else {
    const float* fp = (const float*)features + (size_t)arow * kH;
#pragma unroll
    for (int ks = 0; ks < 4; ++ks) {
      f32x4 x0 = *(const f32x4*)(fp + ks * 32 + q * 8);
      f32x4 x1 = *(const f32x4*)(fp + ks * 32 + q * 8 + 4);
      bf16x8 ahi, alo;
#pragma unroll
      for (int e = 0; e < 4; ++e) {
        bf16_t h0 = (bf16_t)x0[e]; ahi[e]     = h0; alo[e]     = (bf16_t)(x0[e] - (float)h0);
        bf16_t h1 = (bf16_t)x1[e]; ahi[e + 4] = h1; alo[e + 4] = (bf16_t)(x1[e] - (float)h1);
      }
#pragma unroll
      for (int nt = 0; nt < 8; ++nt) {
        bf16x8 bfr = *(const bf16x8*)(wft + (nt * 16 + n16) * kH + ks * 32 + q * 8);
        acc[nt] = __builtin_amdgcn_mfma_f32_16x16x32_bf16(ahi, bfr, acc[nt], 0, 0, 0);
        acc[nt] = __builtin_amdgcn_mfma_f32_16x16x32_bf16(alo, bfr, acc[nt], 0, 0, 0);
      }
    }
  }
#pragma unroll
  for (int nt = 0; nt < 8; ++nt) {
    const int col = nt * 16 + n16;
    const float bv = ldf(bfv, col, bfm);
#pragma unroll
    for (int r = 0; r < 4; ++r)
      nf[(size_t)(rbase + q * 4 + r) * kF + col] = acc[nt][r] + bv;
  }
}

// ---- main: ballot compaction -> coalesced LDS staging of active rbf rows ->
// ----       per-wave fused tiles: G1 -> softplus -> s_t[wave] -> G2 ->
// ----       nf-weighted register reduce; shuffle+LDS final reduction ----
__global__ __launch_bounds__(256) void main_kernel(
    const void* __restrict__ rbf, const int* __restrict__ nmask,
    const void* __restrict__ b1p, const void* __restrict__ b2p,
    const bf16_t* __restrict__ w1t, const bf16_t* __restrict__ w2t,
    const float* __restrict__ nf, const int* __restrict__ flag,
    float* __restrict__ agg) {
  __shared__ __attribute__((aligned(16))) bf16_t s_a[kN * 64];       // 24576 B, swz: byte ^= (row&7)<<4
  __shared__ __attribute__((aligned(16))) bf16_t s_t[4][16 * 128];   // 16384 B, per-wave, same swizzle
  __shared__ int    s_rows[kN];                                      // 768 B
  __shared__ float  s_red[4][kF];                                    // 2048 B
  __shared__ int    s_bcnt[4];

  const bool bfm = *flag != 0;
  const int bi = blockIdx.x;
  const int b  = bi / kN;
  const int t  = threadIdx.x;
  const int wv = t >> 6, lane = t & 63;
  const int n16 = lane & 15, q = lane >> 4;

  // --- compaction via ballot (deterministic, no atomics) ---
  int active = (t < kN) ? (nmask[bi * kN + t] != 0 ? 1 : 0) : 0;
  unsigned long long bal = __ballot(active != 0);
  if (lane == 0) s_bcnt[wv] = __popcll(bal);
  __syncthreads();
  const int c0 = s_bcnt[0], c1 = s_bcnt[1], c2c = s_bcnt[2];
  const int nm = c0 + c1 + c2c;
  const int prefix = (wv > 0 ? c0 : 0) + (wv > 1 ? c1 : 0) + (wv > 2 ? c2c : 0);
  if (active) {
    int rank = __popcll(bal & ((1ull << lane) - 1ull));
    s_rows[prefix + rank] = t;
  }
  const int ntiles = (nm + 15) >> 4;
  const int tot = ntiles * 16;
  for (int idx = nm + t; idx < tot; idx += 256) s_rows[idx] = 0;  // pad: dup row 0, weight 0
  __syncthreads();

  // --- stage active rows: one coalesced 50-lane row load per wave-iter ---
  char* sab = (char*)s_a;
  for (int idx = wv; idx < tot; idx += 4) {
    const int row = s_rows[idx];
    float v = 0.f;
    if (lane < kG) {
      const size_t off = ((size_t)bi * kN + row) * kG + lane;
      v = bfm ? (float)((const bf16_t*)rbf)[off] : ((const float*)rbf)[off];
    }
    *(bf16_t*)(sab + ((idx * 128 + lane * 2) ^ ((idx & 7) << 4))) = (bf16_t)v;
  }
  __syncthreads();

  float b1r[8], b2r[8];
#pragma unroll
  for (int nt = 0; nt < 8; ++nt) {
    b1r[nt] = ldf(b1p, nt * 16 + n16, bfm);
    b2r[nt] = ldf(b2p, nt * 16 + n16, bfm);
  }

  float racc[8];
#pragma unroll
  for (int nt = 0; nt < 8; ++nt) racc[nt] = 0.f;

  char* tb = (char*)(s_t[wv]);
  const int swA = (n16 & 7) << 4;
  const float* nfb = nf + (size_t)b * kN * kF;

  for (int tt = wv; tt < ntiles; tt += 4) {
    // --- GEMM1: A from s_a (LDS), B = w1t (L2-hot) ---
    const int abase = (tt * 16 + n16) * 128;
    bf16x8 a0 = *(const bf16x8*)(sab + ((abase + q * 16) ^ swA));
    bf16x8 a1 = *(const bf16x8*)(sab + ((abase + 64 + q * 16) ^ swA));

    f32x4 acc[8];
#pragma unroll
    for (int nt = 0; nt < 8; ++nt)
#pragma unroll
      for (int r = 0; r < 4; ++r) acc[nt][r] = 0.f;
#pragma unroll
    for (int nt = 0; nt < 8; ++nt) {
      bf16x8 bfr = *(const bf16x8*)(w1t + (nt * 16 + n16) * 64 + q * 8);
      acc[nt] = __builtin_amdgcn_mfma_f32_16x16x32_bf16(a0, bfr, acc[nt], 0, 0, 0);
    }
#pragma unroll
    for (int nt = 0; nt < 8; ++nt) {
      bf16x8 bfr = *(const bf16x8*)(w1t + (nt * 16 + n16) * 64 + 32 + q * 8);
      acc[nt] = __builtin_amdgcn_mfma_f32_16x16x32_bf16(a1, bfr, acc[nt], 0, 0, 0);
    }

    // --- bias + softplus -> per-wave transpose buffer (C: col=lane&15, row=q*4+r) ---
#pragma unroll
    for (int nt = 0; nt < 8; ++nt) {
      const int colb = (nt * 16 + n16) * 2;
#pragma unroll
      for (int r = 0; r < 4; ++r) {
        const int row = q * 4 + r;
        *(bf16_t*)(tb + ((row * 256 + colb) ^ ((row & 7) << 4))) =
            (bf16_t)softplus_f(acc[nt][r] + b1r[nt]);
      }
    }

    // --- GEMM2: A = Hs tile from s_t[wv], B = w2t ---
    f32x4 c2[8];
#pragma unroll
    for (int nt = 0; nt < 8; ++nt)
#pragma unroll
      for (int r = 0; r < 4; ++r) c2[nt][r] = 0.f;
#pragma unroll
    for (int ks = 0; ks < 4; ++ks) {
      bf16x8 af = *(const bf16x8*)(tb + ((n16 * 256 + ks * 64 + q * 16) ^ swA));
#pragma unroll
      for (int nt = 0; nt < 8; ++nt) {
        bf16x8 bfr = *(const bf16x8*)(w2t + (nt * 16 + n16) * 128 + ks * 32 + q * 8);
        c2[nt] = __builtin_amdgcn_mfma_f32_16x16x32_bf16(af, bfr, c2[nt], 0, 0, 0);
      }
    }

    // --- epilogue: racc[f] += sum_r w[r]*(FW+b2)*nf[j_r,f] ---
    const int i0 = tt * 16 + q * 4;
    int jr[4]; float wr[4];
#pragma unroll
    for (int r = 0; r < 4; ++r) {
      const int idx = i0 + r;
      jr[r] = s_rows[idx];
      wr[r] = (idx < nm) ? 1.f : 0.f;
    }
#pragma unroll
    for (int nt = 0; nt < 8; ++nt) {
      const int f = nt * 16 + n16;
      float p = 0.f;
#pragma unroll
      for (int r = 0; r < 4; ++r)
        p = fmaf(wr[r] * (c2[nt][r] + b2r[nt]), nfb[jr[r] * kF + f], p);
      racc[nt] += p;
    }
  }

  // --- reduction: over q via shuffles, over waves via LDS ---
#pragma unroll
  for (int nt = 0; nt < 8; ++nt) {
    racc[nt] += __shfl_xor(racc[nt], 16);
    racc[nt] += __shfl_xor(racc[nt], 32);
  }
  if (lane < 16) {
#pragma unroll
    for (int nt = 0; nt < 8; ++nt) s_red[wv][nt * 16 + lane] = racc[nt];
  }
  __syncthreads();
  if (t < kF)
    agg[(size_t)bi * kF + t] = s_red[0][t] + s_red[1][t] + s_red[2][t] + s_red[3][t];
}

// ---- out = features + softplus(agg@Wo1+bo1)@Wo2+bo2  (MFMA, hi/lo-split agg) ----
__global__ __launch_bounds__(128) void out_kernel(
    const float* __restrict__ agg, const void* __restrict__ features,
    const bf16_t* __restrict__ wo1t, const bf16_t* __restrict__ wo2t,
    const void* __restrict__ bo1, const void* __restrict__ bo2,
    const int* __restrict__ flag, void* __restrict__ out) {
  __shared__ bf16_t s_t[32 * kOutPitch];   // 8704 B
  const bool bfm = *flag != 0;
  const int t = threadIdx.x, wave = t >> 6, lane = t & 63;
  const int n16 = lane & 15, q = lane >> 4;
  const int rb = blockIdx.x * 32 + wave * 16;

  f32x4 acc[8];
#pragma unroll
  for (int nt = 0; nt < 8; ++nt)
#pragma unroll
    for (int r = 0; r < 4; ++r) acc[nt][r] = 0.f;

  const float* ap = agg + (size_t)(rb + n16) * kF;
#pragma unroll
  for (int ks = 0; ks < 4; ++ks) {
    f32x4 x0 = *(const f32x4*)(ap + ks * 32 + q * 8);
    f32x4 x1 = *(const f32x4*)(ap + ks * 32 + q * 8 + 4);
    bf16x8 ahi, alo;
#pragma unroll
    for (int e = 0; e < 4; ++e) {
      bf16_t h0 = (bf16_t)x0[e]; ahi[e]     = h0; alo[e]     = (bf16_t)(x0[e] - (float)h0);
      bf16_t h1 = (bf16_t)x1[e]; ahi[e + 4] = h1; alo[e + 4] = (bf16_t)(x1[e] - (float)h1);
    }
#pragma unroll
    for (int nt = 0; nt < 8; ++nt) {
      bf16x8 bfr = *(const bf16x8*)(wo1t + (nt * 16 + n16) * kF + ks * 32 + q * 8);
      acc[nt] = __builtin_amdgcn_mfma_f32_16x16x32_bf16(ahi, bfr, acc[nt], 0, 0, 0);
      acc[nt] = __builtin_amdgcn_mfma_f32_16x16x32_bf16(alo, bfr, acc[nt], 0, 0, 0);
    }
  }
#pragma unroll
  for (int nt = 0; nt < 8; ++nt) {
    const int col = nt * 16 + n16;
    const float bv = ldf(bo1, col, bfm);
#pragma unroll
    for (int r = 0; r < 4; ++r)
      s_t[(wave * 16 + q * 4 + r) * kOutPitch + col] = (bf16_t)softplus_f(acc[nt][r] + bv);
  }
  __syncthreads();

#pragma unroll
  for (int nt = 0; nt < 8; ++nt)
#pragma unroll
    for (int r = 0; r < 4; ++r) acc[nt][r] = 0.f;
#pragma unroll
  for (int ks = 0; ks < 4; ++ks) {
    bf16x8 afr = *(const bf16x8*)(s_t + (wave * 16 + n16) * kOutPitch + ks * 32 + q * 8);
#pragma unroll
    for (int nt = 0; nt < 8; ++nt) {
      bf16x8 bfr = *(const bf16x8*)(wo2t + (nt * 16 + n16) * kH + ks * 32 + q * 8);
      acc[nt] = __builtin_amdgcn_mfma_f32_16x16x32_bf16(afr, bfr, acc[nt], 0, 0, 0);
    }
  }
#pragma unroll
  for (int nt = 0; nt < 8; ++nt) {
    const int col = nt * 16 + n16;
    const float bv = ldf(bo2, col, bfm);
#pragma unroll
    for (int r = 0; r < 4; ++r) {
      const int row = rb + q * 4 + r;
      float res = ldf(features, (size_t)row * kH + col, bfm) + acc[nt][r] + bv;
      if (bfm) ((bf16_t*)out)[(size_t)row * kH + col] = (bf16_t)res;
      else     ((float*)out)[(size_t)row * kH + col]  = res;
    }
  }
}

extern "C" void kernel_launch(void* const* d_in, const int* in_sizes, int n_in,
                              void* d_out, int out_size, void* d_ws, size_t ws_size,
                              hipStream_t stream) {
  const void* features = d_in[0];
  const void* rbf      = d_in[1];
  const int*  nmask    = (const int*)d_in[2];
  const void* W1  = d_in[3];
  const void* b1  = d_in[4];
  const void* W2  = d_in[5];
  const void* b2  = d_in[6];
  const void* Wf  = d_in[7];
  const void* bfv = d_in[8];
  const void* Wo1 = d_in[9];
  const void* bo1 = d_in[10];
  const void* Wo2 = d_in[11];
  const void* bo2 = d_in[12];

  char* ws = (char*)d_ws;
  float*  nf   = (float*)ws;                   // 3072*128 f32 = 1,572,864 B
  float*  agg  = (float*)(ws + 1572864);       // 1,572,864 B
  bf16_t* w1t  = (bf16_t*)(ws + 3145728);      // 128*64  bf16 = 16,384 B
  bf16_t* w2t  = (bf16_t*)(ws + 3162112);      // 128*128 bf16 = 32,768 B
  bf16_t* wft  = (bf16_t*)(ws + 3194880);      // 32,768 B
  bf16_t* wo1t = (bf16_t*)(ws + 3227648);      // 32,768 B
  bf16_t* wo2t = (bf16_t*)(ws + 3260416);      // 32,768 B
  int*    flag = (int*)(ws + 3293184);         // 4 B

  detect_kernel<<<1, 256, 0, stream>>>((const unsigned int*)rbf, flag);
  prep_kernel<<<288, 256, 0, stream>>>(W1, W2, Wf, Wo1, Wo2, flag, w1t, w2t, wft, wo1t, wo2t);
  nf_kernel<<<96, 128, 0, stream>>>(features, wft, bfv, flag, nf);
  main_kernel<<<kRows, 256, 0, stream>>>(rbf, nmask, b1, b2, w1t, w2t, nf, flag, agg);
  out_kernel<<<96, 128, 0, stream>>>(agg, features, wo1t, wo2t, bo1, bo2, flag, d_out);
}

// Round 4
// 484.037 us; speedup vs baseline: 1.0225x; 1.0225x over previous
//
#include <hip/hip_runtime.h>
#include <hip/hip_bf16.h>

// InteractionBlock: B=16,N=192,H=128,F=128,G=50
//   fw  = softplus(rbf@W1+b1)@W2+b2          [B,N,N,F]   (never materialized)
//   nf  = features@Wf+bf                      [B,N,F]
//   agg = sum_j mask[b,i,j]*fw[b,i,j,:]*nf[b,j,:]
//   out = features + softplus(agg@Wo1+bo1)@Wo2+bo2
//
// v5: proven-components rebuild after v4 correctness failure.
//  - v4 root-cause candidates: pad-fill bug (t<448 w/ 256 threads -> rows
//    37..63 read stale LDS) + unproven staging/nfT code. All eliminated.
//  - A-fragments loaded DIRECTLY from global with v2's proven predicated
//    dword scheme (dense rows, contiguous slab) -> no s_a, no pad, no
//    staging barriers, no swizzle pair to get wrong.
//  - Key fact: each wave's A-tile rows = trow0+n16 (its own 16 rows), so
//    the main loop needs ZERO barriers; waves are independent pipelines.
//  - LDS 19.2KB (per-wave tb + mask + red) -> ~4 blocks/CU.
//  - nf_kernel / out_kernel / prep / detect: v3 verbatim (all passed).

typedef __bf16 bf16_t;
typedef __bf16 bf16x8 __attribute__((ext_vector_type(8)));
typedef float  f32x4  __attribute__((ext_vector_type(4)));
typedef unsigned int uintx4 __attribute__((ext_vector_type(4)));

constexpr int kB = 16, kN = 192, kH = 128, kF = 128, kG = 50;
constexpr int kRows = kB * kN;        // 3072
constexpr int kOutPitch = 136;        // bf16 elems, mult of 8 -> aligned b128

__device__ __forceinline__ float ldf(const void* p, int i, bool bfm) {
  return bfm ? (float)((const bf16_t*)p)[i] : ((const float*)p)[i];
}

__device__ __forceinline__ float softplus_f(float x) {
  float t = __logf(1.f + __expf(fminf(x, 20.f)));
  return x > 20.f ? x : t;
}

// ---- dtype detector: flag=1 if inputs are packed bf16, 0 if fp32 ----
__global__ __launch_bounds__(256) void detect_kernel(const unsigned int* __restrict__ rbf_w,
                                                     int* __restrict__ flag) {
  __shared__ int c_hi, c_zero;
  const int t = threadIdx.x;
  if (t == 0) { c_hi = 0; c_zero = 0; }
  __syncthreads();
  unsigned int w = rbf_w[(size_t)t * 40003u];   // in-bounds for both dtypes
  unsigned int lo = w & 0xFFFFu;
  if (((lo >> 7) & 0xFFu) >= 128u) atomicAdd(&c_hi, 1);   // |bf16| >= 2: impossible for rbf in [0,1)
  if (lo == 0u) atomicAdd(&c_zero, 1);
  __syncthreads();
  if (t == 0) *flag = (c_hi == 0 && c_zero < 200) ? 1 : 0;
}

// ---- transpose all weight matrices into bf16 [n][k] ----
__global__ __launch_bounds__(256) void prep_kernel(
    const void* __restrict__ W1, const void* __restrict__ W2,
    const void* __restrict__ Wf, const void* __restrict__ Wo1,
    const void* __restrict__ Wo2, const int* __restrict__ flag,
    bf16_t* __restrict__ w1t, bf16_t* __restrict__ w2t,
    bf16_t* __restrict__ wft, bf16_t* __restrict__ wo1t,
    bf16_t* __restrict__ wo2t) {
  const bool bfm = *flag != 0;
  int idx = blockIdx.x * 256 + threadIdx.x;
  if (idx < 8192) {                       // w1t [128][64], G padded 50->64 with zeros
    int n = idx >> 6, k = idx & 63;
    w1t[idx] = (k < kG) ? (bf16_t)ldf(W1, k * kF + n, bfm) : (bf16_t)0.f;
  } else if (idx < 8192 + 16384) {        // w2t [128][128]
    int i2 = idx - 8192; int n = i2 >> 7, k = i2 & 127;
    w2t[i2] = (bf16_t)ldf(W2, k * kF + n, bfm);
  } else if (idx < 8192 + 2 * 16384) {    // wft
    int i2 = idx - 8192 - 16384; int n = i2 >> 7, k = i2 & 127;
    wft[i2] = (bf16_t)ldf(Wf, k * kF + n, bfm);
  } else if (idx < 8192 + 3 * 16384) {    // wo1t
    int i2 = idx - 8192 - 2 * 16384; int n = i2 >> 7, k = i2 & 127;
    wo1t[i2] = (bf16_t)ldf(Wo1, k * kH + n, bfm);
  } else if (idx < 8192 + 4 * 16384) {    // wo2t
    int i2 = idx - 8192 - 3 * 16384; int n = i2 >> 7, k = i2 & 127;
    wo2t[i2] = (bf16_t)ldf(Wo2, k * kH + n, bfm);
  }
}

// ---- nf = features @ Wf + bf  (MFMA; fp32 result, row-major [row][f]) ----
// grid 96, block 128 (2 waves x 16 rows)  -- v3 verbatim (passed)
__global__ __launch_bounds__(128) void nf_kernel(const void* __restrict__ features,
                                                 const bf16_t* __restrict__ wft,
                                                 const void* __restrict__ bfv,
                                                 const int* __restrict__ flag,
                                                 float* __restrict__ nf) {
  const bool bfm = *flag != 0;
  const int t = threadIdx.x, wave = t >> 6, lane = t & 63;
  const int n16 = lane & 15, q = lane >> 4;
  const int rbase = blockIdx.x * 32 + wave * 16;
  const int arow = rbase + n16;

  f32x4 acc[8];
#pragma unroll
  for (int nt = 0; nt < 8; ++nt)
#pragma unroll
    for (int r = 0; r < 4; ++r) acc[nt][r] = 0.f;

  if (bfm) {
    const bf16_t* fp = (const bf16_t*)features + (size_t)arow * kH;
#pragma unroll
    for (int ks = 0; ks < 4; ++ks) {
      bf16x8 afr = *(const bf16x8*)(fp + ks * 32 + q * 8);
#pragma unroll
      for (int nt = 0; nt < 8; ++nt) {
        bf16x8 bfr = *(const bf16x8*)(wft + (nt * 16 + n16) * kH + ks * 32 + q * 8);
        acc[nt] = __builtin_amdgcn_mfma_f32_16x16x32_bf16(afr, bfr, acc[nt], 0, 0, 0);
      }
    }
  } else {
    const float* fp = (const float*)features + (size_t)arow * kH;
#pragma unroll
    for (int ks = 0; ks < 4; ++ks) {
      f32x4 x0 = *(const f32x4*)(fp + ks * 32 + q * 8);
      f32x4 x1 = *(const f32x4*)(fp + ks * 32 + q * 8 + 4);
      bf16x8 ahi, alo;
#pragma unroll
      for (int e = 0; e < 4; ++e) {
        bf16_t h0 = (bf16_t)x0[e]; ahi[e]     = h0; alo[e]     = (bf16_t)(x0[e] - (float)h0);
        bf16_t h1 = (bf16_t)x1[e]; ahi[e + 4] = h1; alo[e + 4] = (bf16_t)(x1[e] - (float)h1);
      }
#pragma unroll
      for (int nt = 0; nt < 8; ++nt) {
        bf16x8 bfr = *(const bf16x8*)(wft + (nt * 16 + n16) * kH + ks * 32 + q * 8);
        acc[nt] = __builtin_amdgcn_mfma_f32_16x16x32_bf16(ahi, bfr, acc[nt], 0, 0, 0);
        acc[nt] = __builtin_amdgcn_mfma_f32_16x16x32_bf16(alo, bfr, acc[nt], 0, 0, 0);
      }
    }
  }
  // C layout: col = lane&15, row = q*4 + r
#pragma unroll
  for (int nt = 0; nt < 8; ++nt) {
    const int col = nt * 16 + n16;
    const float bv = ldf(bfv, col, bfm);
#pragma unroll
    for (int r = 0; r < 4; ++r)
      nf[(size_t)(rbase + q * 4 + r) * kF + col] = acc[nt][r] + bv;
  }
}

// ---- main: per (b,i): dense j in thirds of 64; per-wave independent
// ----       pipeline: A from global (v2 loads) -> GEMM1 -> softplus ->
// ----       per-wave tb -> GEMM2 -> mask/nf epilogue. ZERO loop barriers.
__global__ __launch_bounds__(256) void main_kernel(
    const void* __restrict__ rbf, const int* __restrict__ nmask,
    const void* __restrict__ b1p, const void* __restrict__ b2p,
    const bf16_t* __restrict__ w1t, const bf16_t* __restrict__ w2t,
    const float* __restrict__ nf, const int* __restrict__ flag,
    float* __restrict__ agg) {
  __shared__ __attribute__((aligned(16))) bf16_t s_t[4][16 * 128];   // 16384 B, per-wave, XOR swz
  __shared__ float s_mask[kN];                                       // 768 B
  __shared__ float s_red[4][kF];                                     // 2048 B

  const bool bfm = *flag != 0;
  const int bi = blockIdx.x;
  const int b  = bi / kN;
  const int t  = threadIdx.x;
  const int wv = t >> 6, lane = t & 63;
  const int n16 = lane & 15, q = lane >> 4;

  if (t < kN) s_mask[t] = (float)nmask[bi * kN + t];
  __syncthreads();   // the ONLY barrier before the final reduction

  float b1r[8], b2r[8];
#pragma unroll
  for (int nt = 0; nt < 8; ++nt) {
    b1r[nt] = ldf(b1p, nt * 16 + n16, bfm);
    b2r[nt] = ldf(b2p, nt * 16 + n16, bfm);
  }

  float racc[8];
#pragma unroll
  for (int nt = 0; nt < 8; ++nt) racc[nt] = 0.f;

  char* tb = (char*)(s_t[wv]);
  const int swA   = (n16 & 7) << 4;
  const int trow0 = wv * 16;                       // this wave's rows within a third
  const float* nfb = nf + (size_t)b * kN * kF;

  for (int third = 0; third < 3; ++third) {
    // --- A-fragment straight from global (v2-proven predicated dword form) ---
    const int jrow = third * 64 + trow0 + n16;     // this lane's j row
    bf16x8 a0, a1;
    if (bfm) {
      const unsigned int* rp = (const unsigned int*)rbf + (size_t)bi * 4800 + jrow * 25;
      uintx4 u0, u1;
#pragma unroll
      for (int i = 0; i < 4; ++i) u0[i] = rp[q * 4 + i];             // k 0..31: always valid
#pragma unroll
      for (int i = 0; i < 4; ++i) {
        const int d = 16 + q * 4 + i;                                // k 32..63: predicate d<25
        u1[i] = (d < 25) ? rp[d] : 0u;
      }
      a0 = __builtin_bit_cast(bf16x8, u0);
      a1 = __builtin_bit_cast(bf16x8, u1);
    } else {
      const float* rp = (const float*)rbf + (size_t)bi * (kN * kG) + (size_t)jrow * kG;
#pragma unroll
      for (int i = 0; i < 8; ++i) a0[i] = (bf16_t)rp[q * 8 + i];     // k<=31<50
#pragma unroll
      for (int i = 0; i < 8; ++i) {
        const int k1 = 32 + q * 8 + i;
        a1[i] = (bf16_t)((k1 < kG) ? rp[k1] : 0.f);
      }
    }

    // --- GEMM1: rbf-tile @ W1 (w1t zero-padded k 50..63) ---
    f32x4 acc1[8];
#pragma unroll
    for (int nt = 0; nt < 8; ++nt)
#pragma unroll
      for (int r = 0; r < 4; ++r) acc1[nt][r] = 0.f;
#pragma unroll
    for (int nt = 0; nt < 8; ++nt) {
      bf16x8 bf0 = *(const bf16x8*)(w1t + (nt * 16 + n16) * 64 + q * 8);
      acc1[nt] = __builtin_amdgcn_mfma_f32_16x16x32_bf16(a0, bf0, acc1[nt], 0, 0, 0);
    }
#pragma unroll
    for (int nt = 0; nt < 8; ++nt) {
      bf16x8 bf1 = *(const bf16x8*)(w1t + (nt * 16 + n16) * 64 + 32 + q * 8);
      acc1[nt] = __builtin_amdgcn_mfma_f32_16x16x32_bf16(a1, bf1, acc1[nt], 0, 0, 0);
    }

    // --- bias + softplus -> per-wave transpose buffer (C: col=lane&15, row=q*4+r) ---
#pragma unroll
    for (int nt = 0; nt < 8; ++nt) {
      const int colb = (nt * 16 + n16) * 2;
#pragma unroll
      for (int r = 0; r < 4; ++r) {
        const int row = q * 4 + r;
        *(bf16_t*)(tb + ((row * 256 + colb) ^ ((row & 7) << 4))) =
            (bf16_t)softplus_f(acc1[nt][r] + b1r[nt]);
      }
    }

    // --- GEMM2: Hs tile (per-wave LDS) @ W2 ---
    f32x4 c2[8];
#pragma unroll
    for (int nt = 0; nt < 8; ++nt)
#pragma unroll
      for (int r = 0; r < 4; ++r) c2[nt][r] = 0.f;
#pragma unroll
    for (int ks = 0; ks < 4; ++ks) {
      bf16x8 af = *(const bf16x8*)(tb + ((n16 * 256 + ks * 64 + q * 16) ^ swA));
#pragma unroll
      for (int nt = 0; nt < 8; ++nt) {
        bf16x8 bfr = *(const bf16x8*)(w2t + (nt * 16 + n16) * 128 + ks * 32 + q * 8);
        c2[nt] = __builtin_amdgcn_mfma_f32_16x16x32_bf16(af, bfr, c2[nt], 0, 0, 0);
      }
    }

    // --- epilogue: racc[f] += sum_r mask[j]*(FW+b2)*nf[j][f] (j = jb+r dense) ---
    const int jb = third * 64 + trow0 + q * 4;
#pragma unroll
    for (int nt = 0; nt < 8; ++nt) {
      const int f = nt * 16 + n16;
      float p = 0.f;
#pragma unroll
      for (int r = 0; r < 4; ++r) {
        const int j = jb + r;
        p = fmaf(s_mask[j] * (c2[nt][r] + b2r[nt]), nfb[(size_t)j * kF + f], p);
      }
      racc[nt] += p;
    }
  }

  // --- reduction: over q via shuffles, over waves via LDS ---
#pragma unroll
  for (int nt = 0; nt < 8; ++nt) {
    racc[nt] += __shfl_xor(racc[nt], 16);
    racc[nt] += __shfl_xor(racc[nt], 32);
  }
  if (lane < 16) {
#pragma unroll
    for (int nt = 0; nt < 8; ++nt) s_red[wv][nt * 16 + lane] = racc[nt];
  }
  __syncthreads();
  if (t < kF)
    agg[(size_t)bi * kF + t] = s_red[0][t] + s_red[1][t] + s_red[2][t] + s_red[3][t];
}

// ---- out = features + softplus(agg@Wo1+bo1)@Wo2+bo2  (MFMA, hi/lo-split agg) ----
// grid 96, block 128  -- v3 verbatim (passed)
__global__ __launch_bounds__(128) void out_kernel(
    const float* __restrict__ agg, const void* __restrict__ features,
    const bf16_t* __restrict__ wo1t, const bf16_t* __restrict__ wo2t,
    const void* __restrict__ bo1, const void* __restrict__ bo2,
    const int* __restrict__ flag, void* __restrict__ out) {
  __shared__ bf16_t s_t[32 * kOutPitch];   // 8704 B
  const bool bfm = *flag != 0;
  const int t = threadIdx.x, wave = t >> 6, lane = t & 63;
  const int n16 = lane & 15, q = lane >> 4;
  const int rb = blockIdx.x * 32 + wave * 16;

  f32x4 acc[8];
#pragma unroll
  for (int nt = 0; nt < 8; ++nt)
#pragma unroll
    for (int r = 0; r < 4; ++r) acc[nt][r] = 0.f;

  const float* ap = agg + (size_t)(rb + n16) * kF;
#pragma unroll
  for (int ks = 0; ks < 4; ++ks) {
    f32x4 x0 = *(const f32x4*)(ap + ks * 32 + q * 8);
    f32x4 x1 = *(const f32x4*)(ap + ks * 32 + q * 8 + 4);
    bf16x8 ahi, alo;
#pragma unroll
    for (int e = 0; e < 4; ++e) {
      bf16_t h0 = (bf16_t)x0[e]; ahi[e]     = h0; alo[e]     = (bf16_t)(x0[e] - (float)h0);
      bf16_t h1 = (bf16_t)x1[e]; ahi[e + 4] = h1; alo[e + 4] = (bf16_t)(x1[e] - (float)h1);
    }
#pragma unroll
    for (int nt = 0; nt < 8; ++nt) {
      bf16x8 bfr = *(const bf16x8*)(wo1t + (nt * 16 + n16) * kF + ks * 32 + q * 8);
      acc[nt] = __builtin_amdgcn_mfma_f32_16x16x32_bf16(ahi, bfr, acc[nt], 0, 0, 0);
      acc[nt] = __builtin_amdgcn_mfma_f32_16x16x32_bf16(alo, bfr, acc[nt], 0, 0, 0);
    }
  }
#pragma unroll
  for (int nt = 0; nt < 8; ++nt) {
    const int col = nt * 16 + n16;
    const float bv = ldf(bo1, col, bfm);
#pragma unroll
    for (int r = 0; r < 4; ++r)
      s_t[(wave * 16 + q * 4 + r) * kOutPitch + col] = (bf16_t)softplus_f(acc[nt][r] + bv);
  }
  __syncthreads();

#pragma unroll
  for (int nt = 0; nt < 8; ++nt)
#pragma unroll
    for (int r = 0; r < 4; ++r) acc[nt][r] = 0.f;
#pragma unroll
  for (int ks = 0; ks < 4; ++ks) {
    bf16x8 afr = *(const bf16x8*)(s_t + (wave * 16 + n16) * kOutPitch + ks * 32 + q * 8);
#pragma unroll
    for (int nt = 0; nt < 8; ++nt) {
      bf16x8 bfr = *(const bf16x8*)(wo2t + (nt * 16 + n16) * kH + ks * 32 + q * 8);
      acc[nt] = __builtin_amdgcn_mfma_f32_16x16x32_bf16(afr, bfr, acc[nt], 0, 0, 0);
    }
  }
#pragma unroll
  for (int nt = 0; nt < 8; ++nt) {
    const int col = nt * 16 + n16;
    const float bv = ldf(bo2, col, bfm);
#pragma unroll
    for (int r = 0; r < 4; ++r) {
      const int row = rb + q * 4 + r;
      float res = ldf(features, (size_t)row * kH + col, bfm) + acc[nt][r] + bv;
      if (bfm) ((bf16_t*)out)[(size_t)row * kH + col] = (bf16_t)res;
      else     ((float*)out)[(size_t)row * kH + col]  = res;
    }
  }
}

extern "C" void kernel_launch(void* const* d_in, const int* in_sizes, int n_in,
                              void* d_out, int out_size, void* d_ws, size_t ws_size,
                              hipStream_t stream) {
  const void* features = d_in[0];
  const void* rbf      = d_in[1];
  const int*  nmask    = (const int*)d_in[2];
  const void* W1  = d_in[3];
  const void* b1  = d_in[4];
  const void* W2  = d_in[5];
  const void* b2  = d_in[6];
  const void* Wf  = d_in[7];
  const void* bfv = d_in[8];
  const void* Wo1 = d_in[9];
  const void* bo1 = d_in[10];
  const void* Wo2 = d_in[11];
  const void* bo2 = d_in[12];

  char* ws = (char*)d_ws;
  float*  nf   = (float*)ws;                   // 3072*128 f32 = 1,572,864 B
  float*  agg  = (float*)(ws + 1572864);       // 1,572,864 B
  bf16_t* w1t  = (bf16_t*)(ws + 3145728);      // 128*64  bf16 = 16,384 B
  bf16_t* w2t  = (bf16_t*)(ws + 3162112);      // 128*128 bf16 = 32,768 B
  bf16_t* wft  = (bf16_t*)(ws + 3194880);      // 32,768 B
  bf16_t* wo1t = (bf16_t*)(ws + 3227648);      // 32,768 B
  bf16_t* wo2t = (bf16_t*)(ws + 3260416);      // 32,768 B
  int*    flag = (int*)(ws + 3293184);         // 4 B

  detect_kernel<<<1, 256, 0, stream>>>((const unsigned int*)rbf, flag);
  prep_kernel<<<288, 256, 0, stream>>>(W1, W2, Wf, Wo1, Wo2, flag, w1t, w2t, wft, wo1t, wo2t);
  nf_kernel<<<96, 128, 0, stream>>>(features, wft, bfv, flag, nf);
  main_kernel<<<kRows, 256, 0, stream>>>(rbf, nmask, b1, b2, w1t, w2t, nf, flag, agg);
  out_kernel<<<96, 128, 0, stream>>>(agg, features, wo1t, wo2t, bo1, bo2, flag, d_out);
}

// Round 5
// 420.543 us; speedup vs baseline: 1.1769x; 1.1510x over previous
//
#include <hip/hip_runtime.h>
#include <hip/hip_bf16.h>

// InteractionBlock: B=16,N=192,H=128,F=128,G=50
//   fw  = softplus(rbf@W1+b1)@W2+b2          [B,N,N,F]   (never materialized)
//   nf  = features@Wf+bf                      [B,N,F]
//   agg = sum_j mask[b,i,j]*fw[b,i,j,:]*nf[b,j,:]
//   out = features + softplus(agg@Wo1+bo1)@Wo2+bo2
//
// v6: occupancy rewrite. v5 post-mortem: compiler pipelined the 3-thirds loop
// into 164 VGPR -> 2 waves/SIMD (occupancy steps at 64/128/256) -> 11.6% occ,
// latency-dead. Every version so far was register- or LDS-capped at <=2
// waves/SIMD; that is the invariant to break, not per-wave ILP.
//  - j split 3-ways ACROSS BLOCKS (grid 3072*3): each wave = ONE 16-row tile,
//    straight-line code, no loop to pipeline. __launch_bounds__(256,4) caps
//    at 128 regs -> 4 waves/SIMD.
//  - Partial aggs combined via global f32 atomicAdd (agg zeroed in prep;
//    3 adders/address; fp-order noise << 0.118 threshold).
//  - Mask via per-lane int4 broadcast load; single __syncthreads in kernel.
//  - LDS 18.4KB (per-wave tb + s_red). All math paths v5-verbatim (passed).

typedef __bf16 bf16_t;
typedef __bf16 bf16x8 __attribute__((ext_vector_type(8)));
typedef float  f32x4  __attribute__((ext_vector_type(4)));
typedef unsigned int uintx4 __attribute__((ext_vector_type(4)));

constexpr int kB = 16, kN = 192, kH = 128, kF = 128, kG = 50;
constexpr int kRows = kB * kN;        // 3072
constexpr int kOutPitch = 136;        // bf16 elems, mult of 8 -> aligned b128

__device__ __forceinline__ float ldf(const void* p, int i, bool bfm) {
  return bfm ? (float)((const bf16_t*)p)[i] : ((const float*)p)[i];
}

__device__ __forceinline__ float softplus_f(float x) {
  float t = __logf(1.f + __expf(fminf(x, 20.f)));
  return x > 20.f ? x : t;
}

// ---- dtype detector: flag=1 if inputs are packed bf16, 0 if fp32 ----
__global__ __launch_bounds__(256) void detect_kernel(const unsigned int* __restrict__ rbf_w,
                                                     int* __restrict__ flag) {
  __shared__ int c_hi, c_zero;
  const int t = threadIdx.x;
  if (t == 0) { c_hi = 0; c_zero = 0; }
  __syncthreads();
  unsigned int w = rbf_w[(size_t)t * 40003u];   // in-bounds for both dtypes
  unsigned int lo = w & 0xFFFFu;
  if (((lo >> 7) & 0xFFu) >= 128u) atomicAdd(&c_hi, 1);   // |bf16| >= 2: impossible for rbf in [0,1)
  if (lo == 0u) atomicAdd(&c_zero, 1);
  __syncthreads();
  if (t == 0) *flag = (c_hi == 0 && c_zero < 200) ? 1 : 0;
}

// ---- transpose all weight matrices into bf16 [n][k]; zero agg for atomics ----
__global__ __launch_bounds__(256) void prep_kernel(
    const void* __restrict__ W1, const void* __restrict__ W2,
    const void* __restrict__ Wf, const void* __restrict__ Wo1,
    const void* __restrict__ Wo2, const int* __restrict__ flag,
    bf16_t* __restrict__ w1t, bf16_t* __restrict__ w2t,
    bf16_t* __restrict__ wft, bf16_t* __restrict__ wo1t,
    bf16_t* __restrict__ wo2t, float* __restrict__ agg) {
  const bool bfm = *flag != 0;
  int idx = blockIdx.x * 256 + threadIdx.x;
  // zero agg (main_kernel accumulates into it atomically)
  for (int i = idx; i < kRows * kF; i += 288 * 256) agg[i] = 0.f;
  if (idx < 8192) {                       // w1t [128][64], G padded 50->64 with zeros
    int n = idx >> 6, k = idx & 63;
    w1t[idx] = (k < kG) ? (bf16_t)ldf(W1, k * kF + n, bfm) : (bf16_t)0.f;
  } else if (idx < 8192 + 16384) {        // w2t [128][128]
    int i2 = idx - 8192; int n = i2 >> 7, k = i2 & 127;
    w2t[i2] = (bf16_t)ldf(W2, k * kF + n, bfm);
  } else if (idx < 8192 + 2 * 16384) {    // wft
    int i2 = idx - 8192 - 16384; int n = i2 >> 7, k = i2 & 127;
    wft[i2] = (bf16_t)ldf(Wf, k * kF + n, bfm);
  } else if (idx < 8192 + 3 * 16384) {    // wo1t
    int i2 = idx - 8192 - 2 * 16384; int n = i2 >> 7, k = i2 & 127;
    wo1t[i2] = (bf16_t)ldf(Wo1, k * kH + n, bfm);
  } else if (idx < 8192 + 4 * 16384) {    // wo2t
    int i2 = idx - 8192 - 3 * 16384; int n = i2 >> 7, k = i2 & 127;
    wo2t[i2] = (bf16_t)ldf(Wo2, k * kH + n, bfm);
  }
}

// ---- nf = features @ Wf + bf  (MFMA; fp32 result, row-major [row][f]) ----
// grid 96, block 128 (2 waves x 16 rows)  -- passed twice, verbatim
__global__ __launch_bounds__(128) void nf_kernel(const void* __restrict__ features,
                                                 const bf16_t* __restrict__ wft,
                                                 const void* __restrict__ bfv,
                                                 const int* __restrict__ flag,
                                                 float* __restrict__ nf) {
  const bool bfm = *flag != 0;
  const int t = threadIdx.x, wave = t >> 6, lane = t & 63;
  const int n16 = lane & 15, q = lane >> 4;
  const int rbase = blockIdx.x * 32 + wave * 16;
  const int arow = rbase + n16;

  f32x4 acc[8];
#pragma unroll
  for (int nt = 0; nt < 8; ++nt)
#pragma unroll
    for (int r = 0; r < 4; ++r) acc[nt][r] = 0.f;

  if (bfm) {
    const bf16_t* fp = (const bf16_t*)features + (size_t)arow * kH;
#pragma unroll
    for (int ks = 0; ks < 4; ++ks) {
      bf16x8 afr = *(const bf16x8*)(fp + ks * 32 + q * 8);
#pragma unroll
      for (int nt = 0; nt < 8; ++nt) {
        bf16x8 bfr = *(const bf16x8*)(wft + (nt * 16 + n16) * kH + ks * 32 + q * 8);
        acc[nt] = __builtin_amdgcn_mfma_f32_16x16x32_bf16(afr, bfr, acc[nt], 0, 0, 0);
      }
    }
  } else {
    const float* fp = (const float*)features + (size_t)arow * kH;
#pragma unroll
    for (int ks = 0; ks < 4; ++ks) {
      f32x4 x0 = *(const f32x4*)(fp + ks * 32 + q * 8);
      f32x4 x1 = *(const f32x4*)(fp + ks * 32 + q * 8 + 4);
      bf16x8 ahi, alo;
#pragma unroll
      for (int e = 0; e < 4; ++e) {
        bf16_t h0 = (bf16_t)x0[e]; ahi[e]     = h0; alo[e]     = (bf16_t)(x0[e] - (float)h0);
        bf16_t h1 = (bf16_t)x1[e]; ahi[e + 4] = h1; alo[e + 4] = (bf16_t)(x1[e] - (float)h1);
      }
#pragma unroll
      for (int nt = 0; nt < 8; ++nt) {
        bf16x8 bfr = *(const bf16x8*)(wft + (nt * 16 + n16) * kH + ks * 32 + q * 8);
        acc[nt] = __builtin_amdgcn_mfma_f32_16x16x32_bf16(ahi, bfr, acc[nt], 0, 0, 0);
        acc[nt] = __builtin_amdgcn_mfma_f32_16x16x32_bf16(alo, bfr, acc[nt], 0, 0, 0);
      }
    }
  }
  // C layout: col = lane&15, row = q*4 + r
#pragma unroll
  for (int nt = 0; nt < 8; ++nt) {
    const int col = nt * 16 + n16;
    const float bv = ldf(bfv, col, bfm);
#pragma unroll
    for (int r = 0; r < 4; ++r)
      nf[(size_t)(rbase + q * 4 + r) * kF + col] = acc[nt][r] + bv;
  }
}

// ---- main: block = (b,i,third); wave = ONE 16-row tile, straight-line.
// ----       A from global (proven loads) -> GEMM1 -> softplus -> tb ->
// ----       GEMM2 -> mask/nf epilogue -> reduce -> atomicAdd into agg.
__global__ __launch_bounds__(256, 4) void main_kernel(
    const void* __restrict__ rbf, const int* __restrict__ nmask,
    const void* __restrict__ b1p, const void* __restrict__ b2p,
    const bf16_t* __restrict__ w1t, const bf16_t* __restrict__ w2t,
    const float* __restrict__ nf, const int* __restrict__ flag,
    float* __restrict__ agg) {
  __shared__ __attribute__((aligned(16))) bf16_t s_t[4][16 * 128];   // 16384 B, per-wave, XOR swz
  __shared__ float s_red[4][kF];                                     // 2048 B

  const bool bfm = *flag != 0;
  const int bx = blockIdx.x;
  const int bi = bx / 3, third = bx % 3;     // (b,i) and j-third
  const int b  = bi / kN;
  const int t  = threadIdx.x;
  const int wv = t >> 6, lane = t & 63;
  const int n16 = lane & 15, q = lane >> 4;

  float b1r[8], b2r[8];
#pragma unroll
  for (int nt = 0; nt < 8; ++nt) {
    b1r[nt] = ldf(b1p, nt * 16 + n16, bfm);
    b2r[nt] = ldf(b2p, nt * 16 + n16, bfm);
  }

  // --- A-fragment straight from global (v2/v5-proven predicated dword form) ---
  const int jrow = third * 64 + wv * 16 + n16;     // this lane's j row (absolute)
  bf16x8 a0, a1;
  if (bfm) {
    const unsigned int* rp = (const unsigned int*)rbf + (size_t)bi * 4800 + jrow * 25;
    uintx4 u0, u1;
#pragma unroll
    for (int i = 0; i < 4; ++i) u0[i] = rp[q * 4 + i];             // k 0..31: always valid
#pragma unroll
    for (int i = 0; i < 4; ++i) {
      const int d = 16 + q * 4 + i;                                // k 32..63: predicate d<25
      u1[i] = (d < 25) ? rp[d] : 0u;
    }
    a0 = __builtin_bit_cast(bf16x8, u0);
    a1 = __builtin_bit_cast(bf16x8, u1);
  } else {
    const float* rp = (const float*)rbf + (size_t)bi * (kN * kG) + (size_t)jrow * kG;
#pragma unroll
    for (int i = 0; i < 8; ++i) a0[i] = (bf16_t)rp[q * 8 + i];     // k<=31<50
#pragma unroll
    for (int i = 0; i < 8; ++i) {
      const int k1 = 32 + q * 8 + i;
      a1[i] = (bf16_t)((k1 < kG) ? rp[k1] : 0.f);
    }
  }

  // --- GEMM1: rbf-tile @ W1 (w1t zero-padded k 50..63) ---
  f32x4 acc1[8];
#pragma unroll
  for (int nt = 0; nt < 8; ++nt)
#pragma unroll
    for (int r = 0; r < 4; ++r) acc1[nt][r] = 0.f;
#pragma unroll
  for (int nt = 0; nt < 8; ++nt) {
    bf16x8 bf0 = *(const bf16x8*)(w1t + (nt * 16 + n16) * 64 + q * 8);
    acc1[nt] = __builtin_amdgcn_mfma_f32_16x16x32_bf16(a0, bf0, acc1[nt], 0, 0, 0);
  }
#pragma unroll
  for (int nt = 0; nt < 8; ++nt) {
    bf16x8 bf1 = *(const bf16x8*)(w1t + (nt * 16 + n16) * 64 + 32 + q * 8);
    acc1[nt] = __builtin_amdgcn_mfma_f32_16x16x32_bf16(a1, bf1, acc1[nt], 0, 0, 0);
  }

  // --- bias + softplus -> per-wave transpose buffer (C: col=lane&15, row=q*4+r) ---
  char* tb = (char*)(s_t[wv]);
#pragma unroll
  for (int nt = 0; nt < 8; ++nt) {
    const int colb = (nt * 16 + n16) * 2;
#pragma unroll
    for (int r = 0; r < 4; ++r) {
      const int row = q * 4 + r;
      *(bf16_t*)(tb + ((row * 256 + colb) ^ ((row & 7) << 4))) =
          (bf16_t)softplus_f(acc1[nt][r] + b1r[nt]);
    }
  }

  // --- GEMM2: Hs tile (per-wave LDS) @ W2 ---
  const int swA = (n16 & 7) << 4;
  f32x4 c2[8];
#pragma unroll
  for (int nt = 0; nt < 8; ++nt)
#pragma unroll
    for (int r = 0; r < 4; ++r) c2[nt][r] = 0.f;
#pragma unroll
  for (int ks = 0; ks < 4; ++ks) {
    bf16x8 af = *(const bf16x8*)(tb + ((n16 * 256 + ks * 64 + q * 16) ^ swA));
#pragma unroll
    for (int nt = 0; nt < 8; ++nt) {
      bf16x8 bfr = *(const bf16x8*)(w2t + (nt * 16 + n16) * 128 + ks * 32 + q * 8);
      c2[nt] = __builtin_amdgcn_mfma_f32_16x16x32_bf16(af, bfr, c2[nt], 0, 0, 0);
    }
  }

  // --- epilogue: racc[f] = sum_r mask[j]*(FW+b2)*nf[j][f], j = jb..jb+3 ---
  const int jb = third * 64 + wv * 16 + q * 4;     // absolute j of this lane's 4 rows
  const int4 mv4 = *(const int4*)(nmask + (size_t)bi * kN + jb);   // 16B aligned broadcast
  const int* mvp = (const int*)&mv4;
  const float* nfb = nf + (size_t)b * kN * kF;
  float racc[8];
#pragma unroll
  for (int nt = 0; nt < 8; ++nt) {
    const int f = nt * 16 + n16;
    float p = 0.f;
#pragma unroll
    for (int r = 0; r < 4; ++r) {
      const int j = jb + r;
      p = fmaf((float)mvp[r] * (c2[nt][r] + b2r[nt]), nfb[(size_t)j * kF + f], p);
    }
    racc[nt] = p;
  }

  // --- reduction: over q via shuffles, over waves via LDS, then atomicAdd ---
#pragma unroll
  for (int nt = 0; nt < 8; ++nt) {
    racc[nt] += __shfl_xor(racc[nt], 16);
    racc[nt] += __shfl_xor(racc[nt], 32);
  }
  if (lane < 16) {
#pragma unroll
    for (int nt = 0; nt < 8; ++nt) s_red[wv][nt * 16 + lane] = racc[nt];
  }
  __syncthreads();
  if (t < kF)
    atomicAdd(&agg[(size_t)bi * kF + t],
              s_red[0][t] + s_red[1][t] + s_red[2][t] + s_red[3][t]);
}

// ---- out = features + softplus(agg@Wo1+bo1)@Wo2+bo2  (MFMA, hi/lo-split agg) ----
// grid 96, block 128  -- passed twice, verbatim
__global__ __launch_bounds__(128) void out_kernel(
    const float* __restrict__ agg, const void* __restrict__ features,
    const bf16_t* __restrict__ wo1t, const bf16_t* __restrict__ wo2t,
    const void* __restrict__ bo1, const void* __restrict__ bo2,
    const int* __restrict__ flag, void* __restrict__ out) {
  __shared__ bf16_t s_t[32 * kOutPitch];   // 8704 B
  const bool bfm = *flag != 0;
  const int t = threadIdx.x, wave = t >> 6, lane = t & 63;
  const int n16 = lane & 15, q = lane >> 4;
  const int rb = blockIdx.x * 32 + wave * 16;

  f32x4 acc[8];
#pragma unroll
  for (int nt = 0; nt < 8; ++nt)
#pragma unroll
    for (int r = 0; r < 4; ++r) acc[nt][r] = 0.f;

  const float* ap = agg + (size_t)(rb + n16) * kF;
#pragma unroll
  for (int ks = 0; ks < 4; ++ks) {
    f32x4 x0 = *(const f32x4*)(ap + ks * 32 + q * 8);
    f32x4 x1 = *(const f32x4*)(ap + ks * 32 + q * 8 + 4);
    bf16x8 ahi, alo;
#pragma unroll
    for (int e = 0; e < 4; ++e) {
      bf16_t h0 = (bf16_t)x0[e]; ahi[e]     = h0; alo[e]     = (bf16_t)(x0[e] - (float)h0);
      bf16_t h1 = (bf16_t)x1[e]; ahi[e + 4] = h1; alo[e + 4] = (bf16_t)(x1[e] - (float)h1);
    }
#pragma unroll
    for (int nt = 0; nt < 8; ++nt) {
      bf16x8 bfr = *(const bf16x8*)(wo1t + (nt * 16 + n16) * kF + ks * 32 + q * 8);
      acc[nt] = __builtin_amdgcn_mfma_f32_16x16x32_bf16(ahi, bfr, acc[nt], 0, 0, 0);
      acc[nt] = __builtin_amdgcn_mfma_f32_16x16x32_bf16(alo, bfr, acc[nt], 0, 0, 0);
    }
  }
#pragma unroll
  for (int nt = 0; nt < 8; ++nt) {
    const int col = nt * 16 + n16;
    const float bv = ldf(bo1, col, bfm);
#pragma unroll
    for (int r = 0; r < 4; ++r)
      s_t[(wave * 16 + q * 4 + r) * kOutPitch + col] = (bf16_t)softplus_f(acc[nt][r] + bv);
  }
  __syncthreads();

#pragma unroll
  for (int nt = 0; nt < 8; ++nt)
#pragma unroll
    for (int r = 0; r < 4; ++r) acc[nt][r] = 0.f;
#pragma unroll
  for (int ks = 0; ks < 4; ++ks) {
    bf16x8 afr = *(const bf16x8*)(s_t + (wave * 16 + n16) * kOutPitch + ks * 32 + q * 8);
#pragma unroll
    for (int nt = 0; nt < 8; ++nt) {
      bf16x8 bfr = *(const bf16x8*)(wo2t + (nt * 16 + n16) * kH + ks * 32 + q * 8);
      acc[nt] = __builtin_amdgcn_mfma_f32_16x16x32_bf16(afr, bfr, acc[nt], 0, 0, 0);
    }
  }
#pragma unroll
  for (int nt = 0; nt < 8; ++nt) {
    const int col = nt * 16 + n16;
    const float bv = ldf(bo2, col, bfm);
#pragma unroll
    for (int r = 0; r < 4; ++r) {
      const int row = rb + q * 4 + r;
      float res = ldf(features, (size_t)row * kH + col, bfm) + acc[nt][r] + bv;
      if (bfm) ((bf16_t*)out)[(size_t)row * kH + col] = (bf16_t)res;
      else     ((float*)out)[(size_t)row * kH + col]  = res;
    }
  }
}

extern "C" void kernel_launch(void* const* d_in, const int* in_sizes, int n_in,
                              void* d_out, int out_size, void* d_ws, size_t ws_size,
                              hipStream_t stream) {
  const void* features = d_in[0];
  const void* rbf      = d_in[1];
  const int*  nmask    = (const int*)d_in[2];
  const void* W1  = d_in[3];
  const void* b1  = d_in[4];
  const void* W2  = d_in[5];
  const void* b2  = d_in[6];
  const void* Wf  = d_in[7];
  const void* bfv = d_in[8];
  const void* Wo1 = d_in[9];
  const void* bo1 = d_in[10];
  const void* Wo2 = d_in[11];
  const void* bo2 = d_in[12];

  char* ws = (char*)d_ws;
  float*  nf   = (float*)ws;                   // 3072*128 f32 = 1,572,864 B
  float*  agg  = (float*)(ws + 1572864);       // 1,572,864 B (atomic accum)
  bf16_t* w1t  = (bf16_t*)(ws + 3145728);      // 128*64  bf16 = 16,384 B
  bf16_t* w2t  = (bf16_t*)(ws + 3162112);      // 128*128 bf16 = 32,768 B
  bf16_t* wft  = (bf16_t*)(ws + 3194880);      // 32,768 B
  bf16_t* wo1t = (bf16_t*)(ws + 3227648);      // 32,768 B
  bf16_t* wo2t = (bf16_t*)(ws + 3260416);      // 32,768 B
  int*    flag = (int*)(ws + 3293184);         // 4 B

  detect_kernel<<<1, 256, 0, stream>>>((const unsigned int*)rbf, flag);
  prep_kernel<<<288, 256, 0, stream>>>(W1, W2, Wf, Wo1, Wo2, flag, w1t, w2t, wft, wo1t, wo2t, agg);
  nf_kernel<<<96, 128, 0, stream>>>(features, wft, bfv, flag, nf);
  main_kernel<<<kRows * 3, 256, 0, stream>>>(rbf, nmask, b1, b2, w1t, w2t, nf, flag, agg);
  out_kernel<<<96, 128, 0, stream>>>(agg, features, wo1t, wo2t, bo1, bo2, flag, d_out);
}